// Round 1
// baseline (737.332 us; speedup 1.0000x reference)
//
#include <hip/hip_runtime.h>

#define D 256
#define K 1024
#define NVEC 65536
#define ROWS 128      // rows per block
#define CT 128        // codes per tile
#define BK 32         // d-chunk staged in LDS
#define LS 132        // LDS row stride: 128 + 4 pad, 528 B keeps 16B alignment

// ws layout: ws[0..1023] = ||e_k||^2, ws[1024] = loss accumulator

__global__ void vq_norms_kernel(const float* __restrict__ cb, float* __restrict__ cnorm) {
    const int k = blockIdx.x;
    const int l = threadIdx.x;  // 64 threads = 1 wave
    const float* row = cb + k * D;
    float s = 0.f;
#pragma unroll
    for (int j = 0; j < D; j += 64) {
        float v = row[j + l];
        s += v * v;
    }
#pragma unroll
    for (int off = 32; off > 0; off >>= 1) s += __shfl_down(s, off, 64);
    if (l == 0) cnorm[k] = s;
    if (k == 0 && l == 0) cnorm[K] = 0.f;  // zero the loss accumulator (ws is poisoned 0xAA)
}

__global__ __launch_bounds__(256) void vq_main_kernel(
        const float* __restrict__ x, const float* __restrict__ cb,
        const float* __restrict__ cnorm, float* __restrict__ lossAcc,
        float* __restrict__ out)
{
    __shared__ __align__(16) float xs[BK * LS];   // [dk][row], transposed for b128 frag reads
    __shared__ __align__(16) float cs[BK * LS];   // [dk][code]
    __shared__ int widx[ROWS];
    __shared__ float wsum[4];

    const int tid = threadIdx.x;
    const int tx = tid & 15;      // code sub-tile
    const int ty = tid >> 4;      // row sub-tile
    const int rowBase = blockIdx.x * ROWS;
    const float* xblk = x + (size_t)rowBase * D;

    // running per-row best over this thread's code slice
    float best[8];
    int bidx[8];
#pragma unroll
    for (int i = 0; i < 8; ++i) { best[i] = 3.4e38f; bidx[i] = 0; }

    for (int t = 0; t < K / CT; ++t) {
        const int cbase = t * CT;
        float acc[8][8];
#pragma unroll
        for (int i = 0; i < 8; ++i)
#pragma unroll
            for (int j = 0; j < 8; ++j) acc[i][j] = 0.f;

        for (int kb = 0; kb < D; kb += BK) {
            __syncthreads();  // protect LDS from previous iteration's readers
            // stage x chunk: 128 rows x 32 d (global-coalesced reads, transposed writes)
            for (int e = tid; e < ROWS * BK; e += 256) {
                int r = e >> 5, dk = e & 31;
                xs[dk * LS + r] = xblk[r * D + kb + dk];
            }
            // stage codebook chunk: 128 codes x 32 d
            for (int e = tid; e < CT * BK; e += 256) {
                int c = e >> 5, dk = e & 31;
                cs[dk * LS + c] = cb[(size_t)(cbase + c) * D + kb + dk];
            }
            __syncthreads();
#pragma unroll
            for (int dk = 0; dk < BK; ++dk) {
                const float4 xa  = *(const float4*)&xs[dk * LS + ty * 8];
                const float4 xb  = *(const float4*)&xs[dk * LS + ty * 8 + 4];
                const float4 ca  = *(const float4*)&cs[dk * LS + tx * 8];
                const float4 cb4 = *(const float4*)&cs[dk * LS + tx * 8 + 4];
                const float xr[8] = {xa.x, xa.y, xa.z, xa.w, xb.x, xb.y, xb.z, xb.w};
                const float cr[8] = {ca.x, ca.y, ca.z, ca.w, cb4.x, cb4.y, cb4.z, cb4.w};
#pragma unroll
                for (int i = 0; i < 8; ++i)
#pragma unroll
                    for (int j = 0; j < 8; ++j)
                        acc[i][j] += xr[i] * cr[j];
            }
        }
        // tile epilogue: distances (|x|^2 dropped — constant per row) + running argmin.
        // j ascending + t ascending => codes visited in ascending order per thread;
        // strict '<' keeps lowest index on exact ties (numpy argmin semantics).
#pragma unroll
        for (int j = 0; j < 8; ++j) {
            const int c = cbase + tx * 8 + j;
            const float cn = cnorm[c];
#pragma unroll
            for (int i = 0; i < 8; ++i) {
                float dist = cn - 2.f * acc[i][j];
                if (dist < best[i]) { best[i] = dist; bidx[i] = c; }
            }
        }
    }

    // cross-thread argmin reduce: 16 tx candidates per row (alias red buf over cs)
    __syncthreads();
    float* rdist = cs;
    int* ridx = (int*)cs + 2048;
#pragma unroll
    for (int i = 0; i < 8; ++i) {
        int r = ty * 8 + i;
        rdist[r * 16 + tx] = best[i];
        ridx[r * 16 + tx] = bidx[i];
    }
    __syncthreads();
    if (tid < ROWS) {
        float b = rdist[tid * 16];
        int bi = ridx[tid * 16];
#pragma unroll
        for (int j = 1; j < 16; ++j) {
            float d2 = rdist[tid * 16 + j];
            int id = ridx[tid * 16 + j];
            if (d2 < b || (d2 == b && id < bi)) { b = d2; bi = id; }
        }
        widx[tid] = bi;
    }
    __syncthreads();

    // gather codebook[winner] -> out, accumulate loss partial
    float part = 0.f;
    for (int e = tid; e < ROWS * D; e += 256) {
        int r = e >> 8;
        int d = e & 255;
        float q = cb[(size_t)widx[r] * D + d];
        float xv = xblk[e];
        out[(size_t)rowBase * D + e] = q;
        float df = q - xv;
        part += df * df;
    }
#pragma unroll
    for (int off = 32; off > 0; off >>= 1) part += __shfl_down(part, off, 64);
    if ((tid & 63) == 0) wsum[tid >> 6] = part;
    __syncthreads();
    if (tid == 0) atomicAdd(lossAcc, wsum[0] + wsum[1] + wsum[2] + wsum[3]);
}

__global__ void vq_final_kernel(const float* __restrict__ lossAcc, float* __restrict__ outLoss) {
    // loss = q_latent + 0.25*e_latent = 1.25 * mean((q-x)^2); mean over N*D = 16777216
    *outLoss = 1.25f * (*lossAcc) / 16777216.f;
}

extern "C" void kernel_launch(void* const* d_in, const int* in_sizes, int n_in,
                              void* d_out, int out_size, void* d_ws, size_t ws_size,
                              hipStream_t stream) {
    const float* x  = (const float*)d_in[0];   // [64,32,32,256] = [65536,256]
    const float* cb = (const float*)d_in[1];   // [1024,256]
    float* out = (float*)d_out;                // quantized [16777216] then loss [1]
    float* cnorm = (float*)d_ws;               // [1024] + loss accumulator at [1024]
    float* lossAcc = cnorm + K;

    vq_norms_kernel<<<K, 64, 0, stream>>>(cb, cnorm);
    vq_main_kernel<<<NVEC / ROWS, 256, 0, stream>>>(x, cb, cnorm, lossAcc, out);
    vq_final_kernel<<<1, 1, 0, stream>>>(lossAcc, out + (size_t)NVEC * D);
}

// Round 2
// 331.400 us; speedup vs baseline: 2.2249x; 2.2249x over previous
//
#include <hip/hip_runtime.h>

#define D 256
#define K 1024
#define NVEC 65536
#define ROWS 128      // rows per block
#define CT 128        // codes per tile
#define BK 32         // k-chunk staged per iteration
#define LSTRIDE 56    // ushort stride: 112 B/row, 16B-aligned, row*28 words %32 spreads 8 banks
#define NTILE (K / CT)
#define NKB (D / BK)
#define MARGIN 2.0f   // >> 22 sigma of bf16 coarse distance error (sigma~0.09)
#define MAXCAND 16

typedef __attribute__((ext_vector_type(8))) __bf16 bf16x8;
typedef __attribute__((ext_vector_type(4))) float floatx4;

__device__ inline unsigned short f2bf(float f) {  // RNE fp32->bf16
    unsigned int u = __float_as_uint(f);
    unsigned int r = u + 0x7fffu + ((u >> 16) & 1u);
    return (unsigned short)(r >> 16);
}
// order-preserving float->uint key (handles negatives)
__device__ inline unsigned int fkey(float f) {
    unsigned int b = __float_as_uint(f);
    return (b & 0x80000000u) ? ~b : (b | 0x80000000u);
}
__device__ inline float unfkey(unsigned int k) {
    unsigned int b = (k & 0x80000000u) ? (k & 0x7fffffffu) : ~k;
    return __uint_as_float(b);
}

// ws: [0..1023] ||e_k||^2, [1024] loss accumulator
__global__ void vq_norms_kernel(const float* __restrict__ cb, float* __restrict__ cnorm) {
    const int k = blockIdx.x;
    const int l = threadIdx.x;
    const float* row = cb + k * D;
    float s = 0.f;
#pragma unroll
    for (int j = 0; j < D; j += 64) { float v = row[j + l]; s += v * v; }
#pragma unroll
    for (int off = 32; off > 0; off >>= 1) s += __shfl_down(s, off, 64);
    if (l == 0) cnorm[k] = s;
    if (k == 0 && l == 0) cnorm[K] = 0.f;
}

__global__ __launch_bounds__(256) void vq_main_kernel(
        const float* __restrict__ x, const float* __restrict__ cb,
        const float* __restrict__ cnorm, float* __restrict__ lossAcc,
        float* __restrict__ out)
{
    __shared__ __align__(16) unsigned short xs[ROWS * LSTRIDE];  // bf16 bits, [row][k]
    __shared__ __align__(16) unsigned short cs[CT * LSTRIDE];    // bf16 bits, [code][k]
    __shared__ unsigned long long rowPack[ROWS];  // (fkey(coarse min)<<32)|code
    __shared__ float rowMinF[ROWS];
    __shared__ int ccnt[ROWS];
    __shared__ int cand[ROWS][MAXCAND];
    __shared__ int widx[ROWS];
    __shared__ float wsum[4];

    const int tid = threadIdx.x;
    const int wave = tid >> 6;
    const int lane = tid & 63;
    const int quad = lane >> 4;
    const int col  = lane & 15;
    const int wr = wave >> 1;   // row half (0/1): rows wr*64..+64
    const int wc = wave & 1;    // code half (0/1): codes wc*64..+64 of tile
    const int rowBase = blockIdx.x * ROWS;
    const float* xblk = x + (size_t)rowBase * D;

    if (tid < ROWS) { rowPack[tid] = ~0ull; ccnt[tid] = 0; }

    for (int t = 0; t < NTILE; ++t) {
        floatx4 acc[4][4];
#pragma unroll
        for (int i = 0; i < 4; ++i)
#pragma unroll
            for (int j = 0; j < 4; ++j) acc[i][j] = (floatx4){0.f, 0.f, 0.f, 0.f};

        for (int kb = 0; kb < NKB; ++kb) {
            __syncthreads();  // also covers rowPack/ccnt init on first iter
            // stage x chunk: 128 rows x 32 k, fp32->bf16
#pragma unroll
            for (int it = 0; it < 4; ++it) {
                int idx = tid + it * 256;           // 0..1023, 8 float4 per row
                int r = idx >> 3, kq = (idx & 7) * 4;
                float4 v = *(const float4*)&xblk[r * D + kb * BK + kq];
                ushort4 h = make_ushort4(f2bf(v.x), f2bf(v.y), f2bf(v.z), f2bf(v.w));
                *(ushort4*)&xs[r * LSTRIDE + kq] = h;
            }
            // stage codebook chunk: 128 codes x 32 k
#pragma unroll
            for (int it = 0; it < 4; ++it) {
                int idx = tid + it * 256;
                int c = idx >> 3, kq = (idx & 7) * 4;
                float4 v = *(const float4*)&cb[(size_t)(t * CT + c) * D + kb * BK + kq];
                ushort4 h = make_ushort4(f2bf(v.x), f2bf(v.y), f2bf(v.z), f2bf(v.w));
                *(ushort4*)&cs[c * LSTRIDE + kq] = h;
            }
            __syncthreads();
            // fragments: A[m][k] m=lane&15,k=quad*8+j ; B[n][k] same (gemm_bt layout)
            bf16x8 af[4], bf[4];
#pragma unroll
            for (int i = 0; i < 4; ++i)
                af[i] = *(const bf16x8*)&xs[(wr * 64 + i * 16 + col) * LSTRIDE + quad * 8];
#pragma unroll
            for (int j = 0; j < 4; ++j)
                bf[j] = *(const bf16x8*)&cs[(wc * 64 + j * 16 + col) * LSTRIDE + quad * 8];
#pragma unroll
            for (int i = 0; i < 4; ++i)
#pragma unroll
                for (int j = 0; j < 4; ++j)
                    acc[i][j] = __builtin_amdgcn_mfma_f32_16x16x32_bf16(af[i], bf[j], acc[i][j], 0, 0, 0);
        }

        // ---- tile epilogue: coarse distances, running per-row min ----
        const int cbase = t * CT + wc * 64;
        float cn[4];
#pragma unroll
        for (int j = 0; j < 4; ++j) cn[j] = cnorm[cbase + j * 16 + col];

#pragma unroll
        for (int i = 0; i < 4; ++i) {
#pragma unroll
            for (int reg = 0; reg < 4; ++reg) {
                // D-layout: col=lane&15, row=quad*4+reg (within 16x16 frag)
                float best = cn[0] - 2.f * acc[i][0][reg];
                int bidx = cbase + col;
#pragma unroll
                for (int j = 1; j < 4; ++j) {
                    float d2 = cn[j] - 2.f * acc[i][j][reg];
                    int id = cbase + j * 16 + col;
                    if (d2 < best) { best = d2; bidx = id; }  // j asc => lowest idx on tie
                }
#pragma unroll
                for (int off = 1; off < 16; off <<= 1) {
                    float ob = __shfl_xor(best, off, 64);
                    int oi = __shfl_xor(bidx, off, 64);
                    if (ob < best || (ob == best && oi < bidx)) { best = ob; bidx = oi; }
                }
                if (col == 0) {
                    int row = wr * 64 + i * 16 + quad * 4 + reg;
                    unsigned long long pack = ((unsigned long long)fkey(best) << 32) | (unsigned int)bidx;
                    atomicMin(&rowPack[row], pack);
                }
            }
        }
        __syncthreads();
        if (tid < ROWS) rowMinF[tid] = unfkey((unsigned int)(rowPack[tid] >> 32));
        __syncthreads();
        // candidate collection vs running min (superset of final-margin set)
#pragma unroll
        for (int i = 0; i < 4; ++i)
#pragma unroll
            for (int reg = 0; reg < 4; ++reg) {
                int row = wr * 64 + i * 16 + quad * 4 + reg;
                float lim = rowMinF[row] + MARGIN;
#pragma unroll
                for (int j = 0; j < 4; ++j) {
                    float d2 = cn[j] - 2.f * acc[i][j][reg];
                    if (d2 < lim) {
                        int slot = atomicAdd(&ccnt[row], 1);
                        if (slot < MAXCAND) cand[row][slot] = cbase + j * 16 + col;
                    }
                }
            }
        // next tile's first staging barrier orders these LDS writes
    }
    __syncthreads();

    // ---- exact fp32 rescore of candidates: wave w handles rows w*32..+32 ----
    for (int rr = 0; rr < 32; ++rr) {
        const int r = wave * 32 + rr;
        int m = ccnt[r]; if (m > MAXCAND) m = MAXCAND;
        const float4 xv = *(const float4*)&xblk[r * D + lane * 4];
        float best = 3.4e38f;
        int bi = 0x7fffffff;
        for (int c = 0; c < m; ++c) {
            const int code = cand[r][c];
            const float4 ev = *(const float4*)&cb[(size_t)code * D + lane * 4];
            float p = xv.x * ev.x + xv.y * ev.y + xv.z * ev.z + xv.w * ev.w;
#pragma unroll
            for (int off = 1; off < 64; off <<= 1) p += __shfl_xor(p, off, 64);
            float dist = cnorm[code] - 2.f * p;
            if (dist < best || (dist == best && code < bi)) { best = dist; bi = code; }
        }
        if (lane == 0) widx[r] = (m > 0) ? bi : (int)(rowPack[r] & 0xffffffffu);
    }
    __syncthreads();

    // ---- gather + loss ----
    float part = 0.f;
#pragma unroll
    for (int it = 0; it < 32; ++it) {
        int e4 = tid + it * 256;          // ROWS*D/4 = 8192 float4
        int r = e4 >> 6, d4 = (e4 & 63) * 4;
        float4 q = *(const float4*)&cb[(size_t)widx[r] * D + d4];
        float4 xv = *(const float4*)&xblk[r * D + d4];
        *(float4*)&out[(size_t)rowBase * D + r * D + d4] = q;
        float a = q.x - xv.x, b = q.y - xv.y, c2 = q.z - xv.z, d2 = q.w - xv.w;
        part += a * a + b * b + c2 * c2 + d2 * d2;
    }
#pragma unroll
    for (int off = 32; off > 0; off >>= 1) part += __shfl_down(part, off, 64);
    if (lane == 0) wsum[wave] = part;
    __syncthreads();
    if (tid == 0) atomicAdd(lossAcc, wsum[0] + wsum[1] + wsum[2] + wsum[3]);
}

__global__ void vq_final_kernel(const float* __restrict__ lossAcc, float* __restrict__ outLoss) {
    *outLoss = 1.25f * (*lossAcc) / 16777216.f;  // q_latent + 0.25*e_latent
}

extern "C" void kernel_launch(void* const* d_in, const int* in_sizes, int n_in,
                              void* d_out, int out_size, void* d_ws, size_t ws_size,
                              hipStream_t stream) {
    const float* x  = (const float*)d_in[0];
    const float* cb = (const float*)d_in[1];
    float* out = (float*)d_out;
    float* cnorm = (float*)d_ws;
    float* lossAcc = cnorm + K;

    vq_norms_kernel<<<K, 64, 0, stream>>>(cb, cnorm);
    vq_main_kernel<<<NVEC / ROWS, 256, 0, stream>>>(x, cb, cnorm, lossAcc, out);
    vq_final_kernel<<<1, 1, 0, stream>>>(lossAcc, out + (size_t)NVEC * D);
}

// Round 3
// 285.203 us; speedup vs baseline: 2.5853x; 1.1620x over previous
//
#include <hip/hip_runtime.h>

#define D 256
#define K 1024
#define NVEC 65536
#define ROWS 128      // rows per search/resolve block
#define GROUPC 256    // codes per group
#define NG (K / GROUPC)
#define BK 32         // k-chunk per cs stage
#define NKB (D / BK)
#define MARGIN 0.5f   // ~7 sigma of bf16 coarse-distance error (sigma~0.05)
#define MAXC 16

typedef __attribute__((ext_vector_type(8))) __bf16 bf16x8;
typedef __attribute__((ext_vector_type(4))) float floatx4;

__device__ inline unsigned short f2bf(float f) {  // RNE fp32->bf16
    unsigned int u = __float_as_uint(f);
    unsigned int r = u + 0x7fffu + ((u >> 16) & 1u);
    return (unsigned short)(r >> 16);
}
__device__ inline unsigned int fkey(float f) {    // order-preserving float->uint
    unsigned int b = __float_as_uint(f);
    return (b & 0x80000000u) ? ~b : (b | 0x80000000u);
}
__device__ inline float unfkey(unsigned int k) {
    unsigned int b = (k & 0x80000000u) ? (k & 0x7fffffffu) : ~k;
    return __uint_as_float(b);
}
__device__ inline void gl2lds16(const void* g, void* l) {
    __builtin_amdgcn_global_load_lds((const __attribute__((address_space(1))) void*)g,
                                     (__attribute__((address_space(3))) void*)l, 16, 0, 0);
}

// ws layout: cnorm fp32 [0,4KB) | lossAcc @4KB | cbh bf16 @8KB (512KB)
//            ccnt int @1MB (256KB) | cand int @1MB+256KB (65536*16*4 = 4MB)

// ---- K0: codebook norms + bf16 convert + zero loss ----
__global__ void vq_prep_cb(const float* __restrict__ cb, float* __restrict__ cnorm,
                           unsigned short* __restrict__ cbh, float* __restrict__ lossAcc) {
    const int k = blockIdx.x;
    const int l = threadIdx.x;
    float4 v = *(const float4*)&cb[k * D + l * 4];
    *(ushort4*)&cbh[k * D + l * 4] = make_ushort4(f2bf(v.x), f2bf(v.y), f2bf(v.z), f2bf(v.w));
    float s = v.x * v.x + v.y * v.y + v.z * v.z + v.w * v.w;
#pragma unroll
    for (int off = 32; off > 0; off >>= 1) s += __shfl_down(s, off, 64);
    if (l == 0) cnorm[k] = s;
    if (k == 0 && l == 0) *lossAcc = 0.f;
}

// ---- K1: x -> bf16 (into out-buffer high half) ----
__global__ void vq_cvt_x(const float* __restrict__ x, unsigned short* __restrict__ xh) {
    int t = blockIdx.x * 256 + threadIdx.x;
#pragma unroll
    for (int it = 0; it < 4; ++it) {
        int idx = t + it * 1048576;          // 4M float4 total
        float4 v = *(const float4*)&x[idx * 4];
        *(ushort4*)&xh[idx * 4] = make_ushort4(f2bf(v.x), f2bf(v.y), f2bf(v.z), f2bf(v.w));
    }
}

// ---- K2: coarse bf16 MFMA search -> candidate lists ----
__global__ __launch_bounds__(256, 2) void vq_search(
        const unsigned short* __restrict__ xh, const unsigned short* __restrict__ cbh,
        const float* __restrict__ cnorm, int* __restrict__ cntg, int* __restrict__ candg)
{
    __shared__ __align__(16) unsigned short cs[2][GROUPC * BK];  // 2 x 16KB, XOR-swizzled 16B segs
    __shared__ unsigned int rowMinU[ROWS];
    __shared__ int ccnt[ROWS];
    __shared__ int cand[ROWS][MAXC];

    const int tid = threadIdx.x;
    const int wave = tid >> 6;
    const int lane = tid & 63;
    const int quad = lane >> 4;
    const int col  = lane & 15;
    const int RH = wave >> 1;            // row half: rows RH*64..+64
    const int CH = wave & 1;             // code half of group: codes CH*128..+128
    const int rowBase = blockIdx.x * ROWS;

    if (tid < ROWS) { rowMinU[tid] = 0xFFFFFFFFu; ccnt[tid] = 0; }

    for (int g = 0; g < NG; ++g) {
        floatx4 acc[4][8];
#pragma unroll
        for (int i = 0; i < 4; ++i)
#pragma unroll
            for (int j = 0; j < 8; ++j) acc[i][j] = (floatx4){0.f, 0.f, 0.f, 0.f};

        // stage kb=0 into buf 0: slot = c*4+sp holds seg s=(sp-(c>>1))&3 of code c
#pragma unroll
        for (int n = 0; n < 4; ++n) {
            int slot = (wave * 4 + n) * 64 + lane;
            int c = slot >> 2, sp = slot & 3;
            int s = (sp - ((c >> 1) & 3)) & 3;
            gl2lds16(cbh + (size_t)(g * GROUPC + c) * D + 0 * BK + s * 8,
                     (void*)(cs[0] + (size_t)(wave * 4 + n) * 512));
        }

        for (int kb = 0; kb < NKB; ++kb) {
            __syncthreads();   // buf[kb&1] ready (drains global_load_lds); prev readers done
            if (kb < NKB - 1) {
                unsigned short* nb = cs[(kb + 1) & 1];
#pragma unroll
                for (int n = 0; n < 4; ++n) {
                    int slot = (wave * 4 + n) * 64 + lane;
                    int c = slot >> 2, sp = slot & 3;
                    int s = (sp - ((c >> 1) & 3)) & 3;
                    gl2lds16(cbh + (size_t)(g * GROUPC + c) * D + (kb + 1) * BK + s * 8,
                             (void*)(nb + (size_t)(wave * 4 + n) * 512));
                }
            }
            const unsigned short* cb_ = cs[kb & 1];
            // A-frags from global xh: A[m][k] m=lane&15, k=quad*8+j
            bf16x8 af[4];
#pragma unroll
            for (int i = 0; i < 4; ++i)
                af[i] = *(const bf16x8*)(xh + (size_t)(rowBase + RH * 64 + i * 16 + col) * D
                                         + kb * BK + quad * 8);
#pragma unroll
            for (int j = 0; j < 8; ++j) {
                int c = CH * 128 + j * 16 + col;
                int slot = c * 4 + ((quad + ((c >> 1) & 3)) & 3);
                bf16x8 bf = *(const bf16x8*)(cb_ + slot * 8);
#pragma unroll
                for (int i = 0; i < 4; ++i)
                    acc[i][j] = __builtin_amdgcn_mfma_f32_16x16x32_bf16(af[i], bf, acc[i][j], 0, 0, 0);
            }
        }

        // ---- group epilogue (no barriers needed: running-min bound is superset-safe) ----
        const int cbase = g * GROUPC + CH * 128;
        float cn[8];
#pragma unroll
        for (int j = 0; j < 8; ++j) cn[j] = cnorm[cbase + j * 16 + col];

#pragma unroll
        for (int i = 0; i < 4; ++i)
#pragma unroll
            for (int reg = 0; reg < 4; ++reg) {
                float v = 3.4e38f;
#pragma unroll
                for (int j = 0; j < 8; ++j) {
                    float d2 = cn[j] - 2.f * acc[i][j][reg];
                    v = fminf(v, d2);
                }
#pragma unroll
                for (int off = 1; off < 16; off <<= 1)
                    v = fminf(v, __shfl_xor(v, off, 64));
                if (col == 0)
                    atomicMin(&rowMinU[RH * 64 + i * 16 + quad * 4 + reg], fkey(v));
            }
#pragma unroll
        for (int i = 0; i < 4; ++i)
#pragma unroll
            for (int reg = 0; reg < 4; ++reg) {
                int r = RH * 64 + i * 16 + quad * 4 + reg;
                float lim = unfkey(rowMinU[r]) + MARGIN;
#pragma unroll
                for (int j = 0; j < 8; ++j) {
                    float d2 = cn[j] - 2.f * acc[i][j][reg];
                    if (d2 < lim) {
                        int slot = atomicAdd(&ccnt[r], 1);
                        if (slot < MAXC) cand[r][slot] = cbase + j * 16 + col;
                    }
                }
            }
    }
    __syncthreads();
    // dump candidate lists
    if (tid < ROWS) cntg[rowBase + tid] = ccnt[tid];
    {
        int r = tid >> 1, h = (tid & 1) * 8;
        int4* dst = (int4*)&candg[(size_t)(rowBase + r) * MAXC + h];
        const int4* src = (const int4*)&cand[r][h];
        dst[0] = src[0];
        dst[1] = src[1];
    }
}

// ---- K3: exact fp32 rescore + gather + loss ----
__global__ __launch_bounds__(256) void vq_resolve(
        const float* __restrict__ x, const float* __restrict__ cb,
        const float* __restrict__ cnorm, const int* __restrict__ cntg,
        const int* __restrict__ candg, float* __restrict__ lossAcc,
        float* __restrict__ out)
{
    __shared__ int widx[ROWS];
    __shared__ float wsum[4];
    const int tid = threadIdx.x;
    const int wave = tid >> 6;
    const int lane = tid & 63;
    const int rowBase = blockIdx.x * ROWS;
    const float* xblk = x + (size_t)rowBase * D;

    for (int rr = 0; rr < 32; ++rr) {
        const int rl = wave * 32 + rr;
        const int r = rowBase + rl;
        int m = cntg[r]; if (m > MAXC) m = MAXC;
        const float4 xv = *(const float4*)&xblk[rl * D + lane * 4];
        float best = 3.4e38f;
        int bi = 0;
        for (int c = 0; c < m; ++c) {
            const int code = candg[(size_t)r * MAXC + c];
            const float4 ev = *(const float4*)&cb[(size_t)code * D + lane * 4];
            float p = xv.x * ev.x + xv.y * ev.y + xv.z * ev.z + xv.w * ev.w;
#pragma unroll
            for (int off = 1; off < 64; off <<= 1) p += __shfl_xor(p, off, 64);
            float dist = cnorm[code] - 2.f * p;
            if (dist < best || (dist == best && code < bi)) { best = dist; bi = code; }
        }
        if (lane == 0) widx[rl] = bi;
    }
    __syncthreads();

    float part = 0.f;
#pragma unroll
    for (int it = 0; it < 32; ++it) {
        int e4 = tid + it * 256;              // ROWS*D/4 = 8192 float4
        int r = e4 >> 6, d4 = (e4 & 63) * 4;
        float4 q = *(const float4*)&cb[(size_t)widx[r] * D + d4];
        float4 xv = *(const float4*)&xblk[r * D + d4];
        *(float4*)&out[(size_t)rowBase * D + r * D + d4] = q;
        float a = q.x - xv.x, b = q.y - xv.y, c2 = q.z - xv.z, d2 = q.w - xv.w;
        part += a * a + b * b + c2 * c2 + d2 * d2;
    }
#pragma unroll
    for (int off = 32; off > 0; off >>= 1) part += __shfl_down(part, off, 64);
    if (lane == 0) wsum[wave] = part;
    __syncthreads();
    if (tid == 0) atomicAdd(lossAcc, wsum[0] + wsum[1] + wsum[2] + wsum[3]);
}

__global__ void vq_final_kernel(const float* __restrict__ lossAcc, float* __restrict__ outLoss) {
    *outLoss = 1.25f * (*lossAcc) / 16777216.f;  // q_latent + 0.25*e_latent
}

extern "C" void kernel_launch(void* const* d_in, const int* in_sizes, int n_in,
                              void* d_out, int out_size, void* d_ws, size_t ws_size,
                              hipStream_t stream) {
    const float* x  = (const float*)d_in[0];
    const float* cb = (const float*)d_in[1];
    float* out = (float*)d_out;

    float* cnorm = (float*)d_ws;                                   // 4KB
    float* lossAcc = cnorm + K;                                    // @4KB
    unsigned short* cbh = (unsigned short*)((char*)d_ws + 8192);   // 512KB
    int* cntg = (int*)((char*)d_ws + (1 << 20));                   // 256KB
    int* candg = (int*)((char*)d_ws + (1 << 20) + (1 << 18));      // 4MB
    // xh (bf16 x) lives in the out buffer's upper half; vq_resolve overwrites
    // the whole out region afterwards (stream-ordered), reading x from fp32.
    unsigned short* xh = (unsigned short*)((char*)d_out + (32u << 20));

    vq_prep_cb<<<K, 64, 0, stream>>>(cb, cnorm, cbh, lossAcc);
    vq_cvt_x<<<4096, 256, 0, stream>>>(x, xh);
    vq_search<<<NVEC / ROWS, 256, 0, stream>>>(xh, cbh, cnorm, cntg, candg);
    vq_resolve<<<NVEC / ROWS, 256, 0, stream>>>(x, cb, cnorm, cntg, candg, lossAcc, out);
    vq_final_kernel<<<1, 1, 0, stream>>>(lossAcc, out + (size_t)NVEC * D);
}

// Round 5
// 275.924 us; speedup vs baseline: 2.6722x; 1.0336x over previous
//
#include <hip/hip_runtime.h>

#define D 256
#define K 1024
#define NVEC 65536
#define ROWS 64       // rows per block
#define GROUPC 256    // codes per group
#define NG (K / GROUPC)
#define BK 32         // k-chunk staged per iteration
#define NKB (D / BK)
#define MARGIN 0.5f   // ~7 sigma of bf16 coarse-distance error
#define MAXC 12

typedef __attribute__((ext_vector_type(8))) __bf16 bf16x8;
typedef __attribute__((ext_vector_type(4))) float floatx4;

__device__ inline unsigned short f2bf(float f) {  // RNE fp32->bf16
    unsigned int u = __float_as_uint(f);
    unsigned int r = u + 0x7fffu + ((u >> 16) & 1u);
    return (unsigned short)(r >> 16);
}
__device__ inline unsigned int fkey(float f) {    // order-preserving float->uint
    unsigned int b = __float_as_uint(f);
    return (b & 0x80000000u) ? ~b : (b | 0x80000000u);
}
__device__ inline float unfkey(unsigned int k) {
    unsigned int b = (k & 0x80000000u) ? (k & 0x7fffffffu) : ~k;
    return __uint_as_float(b);
}
__device__ inline void gl2lds16(const void* g, void* l) {
    __builtin_amdgcn_global_load_lds((const __attribute__((address_space(1))) void*)g,
                                     (__attribute__((address_space(3))) void*)l, 16, 0, 0);
}

// ws: cnorm fp32 [0,4KB) | lossAcc @4KB | cbh bf16 @8KB (512KB)

__global__ void vq_prep_cb(const float* __restrict__ cb, float* __restrict__ cnorm,
                           unsigned short* __restrict__ cbh, float* __restrict__ lossAcc) {
    const int k = blockIdx.x;
    const int l = threadIdx.x;
    float4 v = *(const float4*)&cb[k * D + l * 4];
    *(ushort4*)&cbh[k * D + l * 4] = make_ushort4(f2bf(v.x), f2bf(v.y), f2bf(v.z), f2bf(v.w));
    float s = v.x * v.x + v.y * v.y + v.z * v.z + v.w * v.w;
#pragma unroll
    for (int off = 32; off > 0; off >>= 1) s += __shfl_down(s, off, 64);
    if (l == 0) cnorm[k] = s;
    if (k == 0 && l == 0) *lossAcc = 0.f;
}

__global__ __launch_bounds__(256, 3) void vq_fused(
        const float* __restrict__ x, const float* __restrict__ cb,
        const unsigned short* __restrict__ cbh, const float* __restrict__ cnorm,
        float* __restrict__ lossAcc, float* __restrict__ out)
{
    __shared__ __align__(16) unsigned short xs[ROWS * D];     // 32 KB, swizzled 16B segs
    __shared__ __align__(16) unsigned short cs[GROUPC * BK];  // 16 KB, swizzled 16B segs
    __shared__ unsigned int rowMinU[ROWS];
    __shared__ int ccnt[ROWS];
    __shared__ int cand[ROWS][MAXC];
    __shared__ int widx[ROWS];
    __shared__ float wsum[4];

    const int tid = threadIdx.x;
    const int wave = tid >> 6;
    const int lane = tid & 63;
    const int quad = lane >> 4;
    const int col  = lane & 15;
    const int rowBase = blockIdx.x * ROWS;
    const float* xblk = x + (size_t)rowBase * D;

    if (tid < ROWS) { rowMinU[tid] = 0xFFFFFFFFu; ccnt[tid] = 0; }

    // ---- stage x -> bf16 LDS once (coalesced fp32 reads, swizzled writes) ----
    // seg = 16B unit (8 bf16) of k; stored at slot = seg ^ (row & 31)
#pragma unroll
    for (int it = 0; it < 16; ++it) {
        int e = tid + it * 256;                 // 4096 float4
        int r = e >> 6;
        int d4 = (e & 63) << 2;                 // float k-offset
        float4 v = *(const float4*)&xblk[r * D + d4];
        int seg = d4 >> 3;
        int slot = seg ^ (r & 31);
        *(ushort4*)&xs[r * D + slot * 8 + (d4 & 4)] =
            make_ushort4(f2bf(v.x), f2bf(v.y), f2bf(v.z), f2bf(v.w));
    }

    // ---- coarse bf16 MFMA search over 4 groups of 256 codes ----
    for (int g = 0; g < NG; ++g) {
        floatx4 acc[4][4];
#pragma unroll
        for (int i = 0; i < 4; ++i)
#pragma unroll
            for (int j = 0; j < 4; ++j) acc[i][j] = (floatx4){0.f, 0.f, 0.f, 0.f};

        for (int kb = 0; kb < NKB; ++kb) {
            __syncthreads();   // prev cs readers done (first iter: xs/init visible)
#pragma unroll
            for (int n = 0; n < 4; ++n) {
                int s16 = (wave * 4 + n) * 64 + lane;      // 1024 16B-slots
                int c = s16 >> 2, sp = s16 & 3;
                int s = (sp - ((c >> 1) & 3)) & 3;
                gl2lds16(cbh + (size_t)(g * GROUPC + c) * D + kb * BK + s * 8,
                         (void*)(cs + (size_t)(wave * 4 + n) * 512));
            }
            __syncthreads();   // cs ready (vmcnt drain)
            bf16x8 af[4];
#pragma unroll
            for (int i = 0; i < 4; ++i) {
                int r = i * 16 + col;
                int slot = (kb * 4 + quad) ^ (r & 31);
                af[i] = *(const bf16x8*)&xs[r * D + slot * 8];
            }
#pragma unroll
            for (int j = 0; j < 4; ++j) {
                int c = wave * 64 + j * 16 + col;
                int slot = c * 4 + ((quad + ((c >> 1) & 3)) & 3);
                bf16x8 bfr = *(const bf16x8*)&cs[slot * 8];
#pragma unroll
                for (int i = 0; i < 4; ++i)
                    acc[i][j] = __builtin_amdgcn_mfma_f32_16x16x32_bf16(af[i], bfr, acc[i][j], 0, 0, 0);
            }
        }

        // ---- group epilogue: running per-row min, then candidate collect ----
        const int cbase = g * GROUPC + wave * 64;
        float cn[4];
#pragma unroll
        for (int j = 0; j < 4; ++j) cn[j] = cnorm[cbase + j * 16 + col];

#pragma unroll
        for (int i = 0; i < 4; ++i)
#pragma unroll
            for (int reg = 0; reg < 4; ++reg) {
                float v = cn[0] - 2.f * acc[i][0][reg];
#pragma unroll
                for (int j = 1; j < 4; ++j)
                    v = fminf(v, cn[j] - 2.f * acc[i][j][reg]);
#pragma unroll
                for (int off = 1; off < 16; off <<= 1)
                    v = fminf(v, __shfl_xor(v, off, 64));
                if (col == 0)
                    atomicMin(&rowMinU[i * 16 + quad * 4 + reg], fkey(v));
            }
        __syncthreads();   // tight bound visible before collect
#pragma unroll
        for (int i = 0; i < 4; ++i)
#pragma unroll
            for (int reg = 0; reg < 4; ++reg) {
                int row = i * 16 + quad * 4 + reg;
                float lim = unfkey(rowMinU[row]) + MARGIN;
#pragma unroll
                for (int j = 0; j < 4; ++j) {
                    float d2 = cn[j] - 2.f * acc[i][j][reg];
                    if (d2 < lim) {
                        int slot = atomicAdd(&ccnt[row], 1);
                        if (slot < MAXC) cand[row][slot] = cbase + j * 16 + col;
                    }
                }
            }
    }
    __syncthreads();

    // ---- exact fp32 rescore (wave w: rows w*16..+16) ----
    for (int rr = 0; rr < 16; ++rr) {
        const int rl = wave * 16 + rr;
        const int m = ccnt[rl];
        float best = 3.4e38f;
        int bi = 0x7fffffff;
        if (m <= MAXC) {
            const float4 xv = *(const float4*)&xblk[rl * D + lane * 4];
            for (int c = 0; c < m; ++c) {
                const int code = cand[rl][c];
                const float4 ev = *(const float4*)&cb[(size_t)code * D + lane * 4];
                float p = xv.x * ev.x + xv.y * ev.y + xv.z * ev.z + xv.w * ev.w;
#pragma unroll
                for (int off = 1; off < 64; off <<= 1) p += __shfl_xor(p, off, 64);
                float dist = cnorm[code] - 2.f * p;
                if (dist < best || (dist == best && code < bi)) { best = dist; bi = code; }
            }
        } else {
            // overflow fallback (~never): exact scan of all K codes, lanes split codes
            for (int c = lane; c < K; c += 64) {
                float p = 0.f;
                for (int k = 0; k < D; ++k) p += xblk[rl * D + k] * cb[(size_t)c * D + k];
                float dist = cnorm[c] - 2.f * p;
                if (dist < best || (dist == best && c < bi)) { best = dist; bi = c; }
            }
#pragma unroll
            for (int off = 1; off < 64; off <<= 1) {
                float ob = __shfl_xor(best, off, 64);
                int oi = __shfl_xor(bi, off, 64);
                if (ob < best || (ob == best && oi < bi)) { best = ob; bi = oi; }
            }
        }
        if (lane == 0) widx[rl] = bi;
    }
    __syncthreads();

    // ---- gather + loss ----
    float part = 0.f;
#pragma unroll
    for (int it = 0; it < 16; ++it) {
        int e4 = tid + it * 256;              // ROWS*D/4 = 4096 float4
        int r = e4 >> 6, d4 = (e4 & 63) * 4;
        float4 q = *(const float4*)&cb[(size_t)widx[r] * D + d4];
        float4 xv = *(const float4*)&xblk[r * D + d4];
        *(float4*)&out[(size_t)rowBase * D + r * D + d4] = q;
        float a = q.x - xv.x, b = q.y - xv.y, c2 = q.z - xv.z, d2 = q.w - xv.w;
        part += a * a + b * b + c2 * c2 + d2 * d2;
    }
#pragma unroll
    for (int off = 32; off > 0; off >>= 1) part += __shfl_down(part, off, 64);
    if (lane == 0) wsum[wave] = part;
    __syncthreads();
    if (tid == 0) atomicAdd(lossAcc, wsum[0] + wsum[1] + wsum[2] + wsum[3]);
}

__global__ void vq_final_kernel(const float* __restrict__ lossAcc, float* __restrict__ outLoss) {
    *outLoss = 1.25f * (*lossAcc) / 16777216.f;  // q_latent + 0.25*e_latent
}

extern "C" void kernel_launch(void* const* d_in, const int* in_sizes, int n_in,
                              void* d_out, int out_size, void* d_ws, size_t ws_size,
                              hipStream_t stream) {
    const float* x  = (const float*)d_in[0];
    const float* cb = (const float*)d_in[1];
    float* out = (float*)d_out;

    float* cnorm = (float*)d_ws;                                  // 4KB
    float* lossAcc = cnorm + K;                                   // @4KB
    unsigned short* cbh = (unsigned short*)((char*)d_ws + 8192);  // 512KB

    vq_prep_cb<<<K, 64, 0, stream>>>(cb, cnorm, cbh, lossAcc);
    vq_fused<<<NVEC / ROWS, 256, 0, stream>>>(x, cb, cbh, cnorm, lossAcc, out);
    vq_final_kernel<<<1, 1, 0, stream>>>(lossAcc, out + (size_t)NVEC * D);
}

// Round 6
// 244.711 us; speedup vs baseline: 3.0131x; 1.1275x over previous
//
#include <hip/hip_runtime.h>

#define D 256
#define K 1024
#define NVEC 65536
#define ROWS 64       // rows per block
#define GROUPC 256    // codes per group (per-wave slice = 64)
#define NG (K / GROUPC)
#define NKB (D / 32)  // 8 k-steps of 32
#define MARGIN 0.5f   // ~7 sigma of bf16 coarse-distance error
#define MAXC 12
#define MAXP (ROWS * MAXC)

typedef __attribute__((ext_vector_type(8))) __bf16 bf16x8;
typedef __attribute__((ext_vector_type(4))) float floatx4;

__device__ inline unsigned short f2bf(float f) {  // RNE fp32->bf16
    unsigned int u = __float_as_uint(f);
    unsigned int r = u + 0x7fffu + ((u >> 16) & 1u);
    return (unsigned short)(r >> 16);
}
__device__ inline unsigned int fkey(float f) {    // order-preserving float->uint
    unsigned int b = __float_as_uint(f);
    return (b & 0x80000000u) ? ~b : (b | 0x80000000u);
}
__device__ inline float unfkey(unsigned int k) {
    unsigned int b = (k & 0x80000000u) ? (k & 0x7fffffffu) : ~k;
    return __uint_as_float(b);
}

// ws: cnorm fp32 [0,4KB) | lossAcc @4KB | cbf bf16 (B-fragment order) @8KB (512KB)

// cbf layout: code c -> g=c>>8, w=(c>>6)&3, j=(c>>4)&3, col=c&15 ; k -> kb=k>>5,
// quad=(k>>3)&3, h=k&7.  16B seg index = S*64 + quad*16+col, S=((g*8+kb)*4+w)*4+j.
// In the k-loop, wave w / group g / kb / j reads seg S*64+lane => base + lane*16B.
__global__ void vq_prep(const float* __restrict__ cb, float* __restrict__ cnorm,
                        unsigned short* __restrict__ cbf, float* __restrict__ lossAcc) {
    const int c = blockIdx.x;
    const int l = threadIdx.x;
    float4 v = *(const float4*)&cb[c * D + l * 4];
    float s = v.x * v.x + v.y * v.y + v.z * v.z + v.w * v.w;
#pragma unroll
    for (int off = 32; off > 0; off >>= 1) s += __shfl_down(s, off, 64);
    if (l == 0) cnorm[c] = s;
    const int g = c >> 8, w = (c >> 6) & 3, j = (c >> 4) & 3, col = c & 15;
    const int kb = l >> 3, quad = (l >> 1) & 3, h = (l & 1) * 4;
    const int S = ((g * 8 + kb) * 4 + w) * 4 + j;
    *(ushort4*)(cbf + (size_t)S * 512 + (quad * 16 + col) * 8 + h) =
        make_ushort4(f2bf(v.x), f2bf(v.y), f2bf(v.z), f2bf(v.w));
    if (c == 0 && l == 0) *lossAcc = 0.f;
}

__global__ __launch_bounds__(256, 4) void vq_fused(
        const float* __restrict__ x, const float* __restrict__ cb,
        const unsigned short* __restrict__ cbf, const float* __restrict__ cnorm,
        float* __restrict__ lossAcc, float* __restrict__ out)
{
    __shared__ __align__(16) unsigned short xs[ROWS * D];   // 32 KB, swizzled 16B segs
    __shared__ unsigned int rowMinU[ROWS];
    __shared__ unsigned long long rowBest[ROWS];
    __shared__ int ccnt[ROWS];
    __shared__ int cand[ROWS][MAXC];
    __shared__ int pairs[MAXP];
    __shared__ int pcnt;
    __shared__ int widx[ROWS];
    __shared__ float wsum[4];

    const int tid = threadIdx.x;
    const int wave = tid >> 6;
    const int lane = tid & 63;
    const int quad = lane >> 4;
    const int col  = lane & 15;
    const int rowBase = blockIdx.x * ROWS;
    const float* xblk = x + (size_t)rowBase * D;

    if (tid < ROWS) { rowMinU[tid] = 0xFFFFFFFFu; rowBest[tid] = ~0ull; ccnt[tid] = 0; }
    if (tid == 0) pcnt = 0;

    // ---- stage x -> bf16 LDS once (seg slot = seg ^ (row & 31)) ----
#pragma unroll
    for (int it = 0; it < 16; ++it) {
        int e = tid + it * 256;                 // 4096 float4
        int r = e >> 6;
        int d4 = (e & 63) << 2;
        float4 v = *(const float4*)&xblk[r * D + d4];
        int slot = (d4 >> 3) ^ (r & 31);
        *(ushort4*)&xs[r * D + slot * 8 + (d4 & 4)] =
            make_ushort4(f2bf(v.x), f2bf(v.y), f2bf(v.z), f2bf(v.w));
    }
    __syncthreads();

    // ---- coarse bf16 MFMA search: barrier-free K-loop, B direct from L2 ----
    for (int g = 0; g < NG; ++g) {
        floatx4 acc[4][4];
#pragma unroll
        for (int i = 0; i < 4; ++i)
#pragma unroll
            for (int j = 0; j < 4; ++j) acc[i][j] = (floatx4){0.f, 0.f, 0.f, 0.f};

#pragma unroll
        for (int kb = 0; kb < NKB; ++kb) {
            bf16x8 af[4], bfr[4];
#pragma unroll
            for (int i = 0; i < 4; ++i) {
                int r = i * 16 + col;
                int slot = (kb * 4 + quad) ^ (r & 31);
                af[i] = *(const bf16x8*)&xs[r * D + slot * 8];
            }
#pragma unroll
            for (int j = 0; j < 4; ++j) {
                int S = ((g * 8 + kb) * 4 + wave) * 4 + j;
                bfr[j] = *(const bf16x8*)(cbf + (size_t)S * 512 + lane * 8);
            }
#pragma unroll
            for (int j = 0; j < 4; ++j)
#pragma unroll
                for (int i = 0; i < 4; ++i)
                    acc[i][j] = __builtin_amdgcn_mfma_f32_16x16x32_bf16(af[i], bfr[j], acc[i][j], 0, 0, 0);
        }

        // ---- group epilogue: running per-row min, then candidate collect ----
        const int cbase = g * GROUPC + wave * 64;
        float cn[4];
#pragma unroll
        for (int j = 0; j < 4; ++j) cn[j] = cnorm[cbase + j * 16 + col];

#pragma unroll
        for (int i = 0; i < 4; ++i)
#pragma unroll
            for (int reg = 0; reg < 4; ++reg) {
                float v = cn[0] - 2.f * acc[i][0][reg];
#pragma unroll
                for (int j = 1; j < 4; ++j)
                    v = fminf(v, cn[j] - 2.f * acc[i][j][reg]);
#pragma unroll
                for (int off = 1; off < 16; off <<= 1)
                    v = fminf(v, __shfl_xor(v, off, 64));
                if (col == 0)
                    atomicMin(&rowMinU[i * 16 + quad * 4 + reg], fkey(v));
            }
        __syncthreads();   // bound includes this group before collect
#pragma unroll
        for (int i = 0; i < 4; ++i)
#pragma unroll
            for (int reg = 0; reg < 4; ++reg) {
                int row = i * 16 + quad * 4 + reg;
                float lim = unfkey(rowMinU[row]) + MARGIN;
#pragma unroll
                for (int j = 0; j < 4; ++j) {
                    float d2 = cn[j] - 2.f * acc[i][j][reg];
                    if (d2 < lim) {
                        int slot = atomicAdd(&ccnt[row], 1);
                        if (slot < MAXC) cand[row][slot] = cbase + j * 16 + col;
                    }
                }
            }
    }
    __syncthreads();

    // ---- build compact (row,code) pair list ----
    if (tid < ROWS) {
        int m = ccnt[tid]; if (m > MAXC) m = MAXC;
        for (int c = 0; c < m; ++c) {
            int p = atomicAdd(&pcnt, 1);
            pairs[p] = (tid << 10) | cand[tid][c];   // can't exceed MAXP by construction
        }
    }
    __syncthreads();
    const int np = pcnt;

    // ---- exact fp32 rescore: 16 lane-teams of 16, one pair per team-step ----
    const int team = wave * 4 + quad;
    for (int p = team; p < np; p += 16) {
        int pr = pairs[p];
        int row = pr >> 10, code = pr & 1023;
        const float* xr = xblk + row * D + col * 16;
        const float* er = cb + (size_t)code * D + col * 16;
        float s = 0.f;
#pragma unroll
        for (int q = 0; q < 4; ++q) {
            float4 a = *(const float4*)(xr + q * 4);
            float4 b = *(const float4*)(er + q * 4);
            s += a.x * b.x + a.y * b.y + a.z * b.z + a.w * b.w;
        }
#pragma unroll
        for (int off = 1; off < 16; off <<= 1) s += __shfl_xor(s, off, 64);
        if (col == 0) {
            float dist = cnorm[code] - 2.f * s;
            unsigned long long pack = ((unsigned long long)fkey(dist) << 32) | (unsigned int)code;
            atomicMin(&rowBest[row], pack);
        }
    }

    // ---- overflow fallback (~never): exact full scan for rows with ccnt > MAXC ----
    for (int rr = 0; rr < 16; ++rr) {
        const int rl = wave * 16 + rr;
        if (ccnt[rl] > MAXC) {
            float best = 3.4e38f;
            int bi = 0x7fffffff;
            for (int c = lane; c < K; c += 64) {
                float p = 0.f;
                for (int k = 0; k < D; ++k) p += xblk[rl * D + k] * cb[(size_t)c * D + k];
                float dist = cnorm[c] - 2.f * p;
                if (dist < best || (dist == best && c < bi)) { best = dist; bi = c; }
            }
#pragma unroll
            for (int off = 1; off < 64; off <<= 1) {
                float ob = __shfl_xor(best, off, 64);
                int oi = __shfl_xor(bi, off, 64);
                if (ob < best || (ob == best && oi < bi)) { best = ob; bi = oi; }
            }
            if (lane == 0)
                atomicMin(&rowBest[rl], ((unsigned long long)fkey(best) << 32) | (unsigned int)bi);
        }
    }
    __syncthreads();
    if (tid < ROWS) widx[tid] = (int)(rowBest[tid] & 0xffffffffu);
    __syncthreads();

    // ---- gather + loss ----
    float part = 0.f;
#pragma unroll
    for (int it = 0; it < 16; ++it) {
        int e4 = tid + it * 256;              // ROWS*D/4 = 4096 float4
        int r = e4 >> 6, d4 = (e4 & 63) * 4;
        float4 q = *(const float4*)&cb[(size_t)widx[r] * D + d4];
        float4 xv = *(const float4*)&xblk[r * D + d4];
        *(float4*)&out[(size_t)rowBase * D + r * D + d4] = q;
        float a = q.x - xv.x, b = q.y - xv.y, c2 = q.z - xv.z, d2 = q.w - xv.w;
        part += a * a + b * b + c2 * c2 + d2 * d2;
    }
#pragma unroll
    for (int off = 32; off > 0; off >>= 1) part += __shfl_down(part, off, 64);
    if (lane == 0) wsum[wave] = part;
    __syncthreads();
    if (tid == 0) atomicAdd(lossAcc, wsum[0] + wsum[1] + wsum[2] + wsum[3]);
}

__global__ void vq_final_kernel(const float* __restrict__ lossAcc, float* __restrict__ outLoss) {
    *outLoss = 1.25f * (*lossAcc) / 16777216.f;  // q_latent + 0.25*e_latent
}

extern "C" void kernel_launch(void* const* d_in, const int* in_sizes, int n_in,
                              void* d_out, int out_size, void* d_ws, size_t ws_size,
                              hipStream_t stream) {
    const float* x  = (const float*)d_in[0];
    const float* cb = (const float*)d_in[1];
    float* out = (float*)d_out;

    float* cnorm = (float*)d_ws;                                  // 4KB
    float* lossAcc = cnorm + K;                                   // @4KB
    unsigned short* cbf = (unsigned short*)((char*)d_ws + 8192);  // 512KB

    vq_prep<<<K, 64, 0, stream>>>(cb, cnorm, cbf, lossAcc);
    vq_fused<<<NVEC / ROWS, 256, 0, stream>>>(x, cb, cbf, cnorm, lossAcc, out);
    vq_final_kernel<<<1, 1, 0, stream>>>(lossAcc, out + (size_t)NVEC * D);
}